// Round 8
// baseline (511.837 us; speedup 1.0000x reference)
//
#include <hip/hip_runtime.h>
#include <math.h>

#define BATCH 32768
#define NCH   2048
#define NCH4  512                 // f32x4 per row
#define NBLK  1024
#define NTHR  256
#define NSUB  8                   // split sum copies (atomic depth 128/addr)
#define RPB   32                  // rows per block, phase 1
#define WIN   64                  // f32x4 windows per thread, phase 2
#define STRIDE (NBLK * NTHR)      // 262144

typedef float f32x4 __attribute__((ext_vector_type(4)));

// ---------------------------------------------------------------------------
// Device-wide barrier (structure proven in R5). All 1024 blocks co-resident:
// __launch_bounds__(256,4) caps VGPR at 128 -> 4 blocks/CU capacity, and the
// kernel's natural usage is far below that (no spill risk: no big arrays).
// cnt/flag zeroed by hipMemsetAsync each call.
// ---------------------------------------------------------------------------
__device__ __forceinline__ void grid_barrier(unsigned* cnt, unsigned* flag) {
    __threadfence();
    __syncthreads();
    if (threadIdx.x == 0) {
        unsigned prev = __hip_atomic_fetch_add(cnt, 1u, __ATOMIC_ACQ_REL,
                                               __HIP_MEMORY_SCOPE_AGENT);
        if (prev == NBLK - 1u) {
            __hip_atomic_store(flag, 1u, __ATOMIC_RELEASE,
                               __HIP_MEMORY_SCOPE_AGENT);
        } else {
            while (__hip_atomic_load(flag, __ATOMIC_ACQUIRE,
                                     __HIP_MEMORY_SCOPE_AGENT) == 0u)
                __builtin_amdgcn_s_sleep(2);
        }
    }
    __syncthreads();
}

// g[c] = (cos(phi-f)*0.5+0.5)^10 + rw * sin(pi*p)^2 * cos(phi) * ws,
// phi = pacc*decay + mean.  Fast trig err ~1e-6 << 0.127 threshold.
__device__ __forceinline__ float gate1(float s, float fr, float pa, float spv,
                                       float dec, float wsc, float rw) {
    float phi = pa * dec + s * (1.0f / (float)BATCH);
    float t  = __cosf(phi - fr) * 0.5f + 0.5f;
    float t2 = t * t, t4 = t2 * t2, t8 = t4 * t4;
    float sp = __sinf((float)M_PI * spv);
    return t8 * t2 + rw * (sp * sp * __cosf(phi) * wsc);
}

// ---------------------------------------------------------------------------
// Persistent fused kernel.
//  P1: block b NT-reads rows [b*32, b*32+32); thread t owns channels
//      8t..8t+7 (f32x4 indices 2t, 2t+1 per row), private accumulation,
//      then 8 device atomicAdds into gsub copy (b & 7).
//  B:  one grid barrier.
//  P2: thread tid gates 64 f32x4 windows at i = tid + j*STRIDE; its channel
//      quad is fixed (c0 = 4*(tid&511)): compute g once from the NSUB sums,
//      then stream with a 4-deep prefetch pipeline, NT loads + NT stores.
// HBM: read x twice (536 MB) + write out (268 MB) — the no-reuse floor.
// ---------------------------------------------------------------------------
__global__ __launch_bounds__(NTHR, 4) void fused_kernel(
        const float* __restrict__ x,
        const float* __restrict__ freqs,
        const float* __restrict__ pdec,
        const float* __restrict__ wscl,
        const float* __restrict__ rwgt,
        const float* __restrict__ pacc,
        const float* __restrict__ spe,
        float* __restrict__ out,
        float* __restrict__ ws) {
    unsigned* cnt  = (unsigned*)ws;          // byte 0
    unsigned* flag = (unsigned*)ws + 32;     // byte 128
    float* gsub    = ws + 1024;              // byte 4096: NSUB*2048 floats

    const int t = threadIdx.x;
    const int b = blockIdx.x;
    const f32x4* __restrict__ x4 = (const f32x4*)x;

    // ---- Phase 1: column sums ----
    {
        size_t base = (size_t)b * (RPB * NCH4) + 2 * t;    // += NCH4 per row
        f32x4 a0 = {0.f, 0.f, 0.f, 0.f};                   // ch 8t..8t+3
        f32x4 a1 = {0.f, 0.f, 0.f, 0.f};                   // ch 8t+4..8t+7

        #pragma unroll 8
        for (int r = 0; r < RPB; ++r) {
            a0 += __builtin_nontemporal_load(&x4[base]);
            a1 += __builtin_nontemporal_load(&x4[base + 1]);
            base += NCH4;
        }

        float* g = gsub + (size_t)(b & (NSUB - 1)) * NCH + 8 * t;
        atomicAdd(g + 0, a0.x); atomicAdd(g + 1, a0.y);
        atomicAdd(g + 2, a0.z); atomicAdd(g + 3, a0.w);
        atomicAdd(g + 4, a1.x); atomicAdd(g + 5, a1.y);
        atomicAdd(g + 6, a1.z); atomicAdd(g + 7, a1.w);
    }

    grid_barrier(cnt, flag);

    // ---- Phase 2: compute this thread's g quad, then gate-stream ----
    const int tid = b * NTHR + t;            // 0..262143
    const int c0 = (tid & 511) * 4;

    f32x4 s = {0.f, 0.f, 0.f, 0.f};
    #pragma unroll
    for (int k = 0; k < NSUB; ++k)
        s += *(const f32x4*)(gsub + (size_t)k * NCH + c0);

    const f32x4 fv = *(const f32x4*)(freqs + c0);
    const f32x4 qv = *(const f32x4*)(pacc + c0);
    const f32x4 ev = *(const f32x4*)(spe + c0);
    const float dec = pdec[0], wsc = wscl[0], rw = rwgt[0];

    f32x4 gv;
    gv.x = gate1(s.x, fv.x, qv.x, ev.x, dec, wsc, rw);
    gv.y = gate1(s.y, fv.y, qv.y, ev.y, dec, wsc, rw);
    gv.z = gate1(s.z, fv.z, qv.z, ev.z, dec, wsc, rw);
    gv.w = gate1(s.w, fv.w, qv.w, ev.w, dec, wsc, rw);

    f32x4* __restrict__ o4 = (f32x4*)out;

#define EMITP(v, jj)                                                      \
    do {                                                                  \
        f32x4 z = (v) * gv;                                               \
        f32x4 o;                                                          \
        o.x = z.x * (1.0f - __expf(-fabsf(z.x)));                         \
        o.y = z.y * (1.0f - __expf(-fabsf(z.y)));                         \
        o.z = z.z * (1.0f - __expf(-fabsf(z.z)));                         \
        o.w = z.w * (1.0f - __expf(-fabsf(z.w)));                         \
        __builtin_nontemporal_store(o, &o4[tid + (size_t)(jj) * STRIDE]); \
    } while (0)

    f32x4 v0 = __builtin_nontemporal_load(&x4[tid + 0 * (size_t)STRIDE]);
    f32x4 v1 = __builtin_nontemporal_load(&x4[tid + 1 * (size_t)STRIDE]);
    f32x4 v2 = __builtin_nontemporal_load(&x4[tid + 2 * (size_t)STRIDE]);
    f32x4 v3 = __builtin_nontemporal_load(&x4[tid + 3 * (size_t)STRIDE]);

    #pragma unroll
    for (int j = 0; j < WIN - 4; j += 4) {
        f32x4 n0 = __builtin_nontemporal_load(&x4[tid + (size_t)(j + 4) * STRIDE]);
        f32x4 n1 = __builtin_nontemporal_load(&x4[tid + (size_t)(j + 5) * STRIDE]);
        f32x4 n2 = __builtin_nontemporal_load(&x4[tid + (size_t)(j + 6) * STRIDE]);
        f32x4 n3 = __builtin_nontemporal_load(&x4[tid + (size_t)(j + 7) * STRIDE]);

        EMITP(v0, j + 0); EMITP(v1, j + 1); EMITP(v2, j + 2); EMITP(v3, j + 3);

        v0 = n0; v1 = n1; v2 = n2; v3 = n3;
    }
    EMITP(v0, WIN - 4); EMITP(v1, WIN - 3); EMITP(v2, WIN - 2); EMITP(v3, WIN - 1);
#undef EMITP
}

extern "C" void kernel_launch(void* const* d_in, const int* in_sizes, int n_in,
                              void* d_out, int out_size, void* d_ws, size_t ws_size,
                              hipStream_t stream) {
    const float* x     = (const float*)d_in[0];
    const float* freqs = (const float*)d_in[1];
    const float* pdec  = (const float*)d_in[2];
    const float* wscl  = (const float*)d_in[3];
    const float* rwgt  = (const float*)d_in[4];
    const float* pacc  = (const float*)d_in[5];
    const float* spe   = (const float*)d_in[6];
    float* out = (float*)d_out;
    float* ws  = (float*)d_ws;

    // Zero barrier words + gsub every call (ws is poisoned once, never
    // restored between replays; kernel must be replay-deterministic).
    hipMemsetAsync(ws, 0, 4096 + NSUB * NCH * sizeof(float), stream);

    fused_kernel<<<NBLK, NTHR, 0, stream>>>(x, freqs, pdec, wscl, rwgt,
                                            pacc, spe, out, ws);
}

// Round 9
// 182.540 us; speedup vs baseline: 2.8040x; 2.8040x over previous
//
#include <hip/hip_runtime.h>
#include <math.h>

#define BATCH 32768
#define NCH   2048
#define NCH4  512                       // f32x4 per row
#define CS_BLOCKS 1024
#define RPB   (BATCH / CS_BLOCKS)       // 32 rows per colsum block
#define NSUB  8                         // split accumulators (atomic depth 128)
#define GATE_BLOCKS 2048
#define STRIDE (GATE_BLOCKS * 256)      // 524288 f32x4 grid stride

typedef float f32x4 __attribute__((ext_vector_type(4)));

// ---------------------------------------------------------------------------
// Pass 1: column sums. Block b reads rows [b*32, b*32+32) with REGULAR loads
// (NT loads proven 5x slower on the R8 fused kernel; regular loads hit full
// BW in R4). Thread t owns channels 8t..8t+7 (f32x4 idx 2t, 2t+1 per row),
// thread-private accumulation, then 8 device atomicAdds into gsub copy
// (b & 7): 1024 blocks / 8 copies = 128-deep per address, ~us total.
// ---------------------------------------------------------------------------
__global__ __launch_bounds__(256) void colsum_kernel(const float* __restrict__ x,
                                                     float* __restrict__ gsub) {
    const int t = threadIdx.x;
    const int b = blockIdx.x;
    const f32x4* __restrict__ x4 = (const f32x4*)x;
    size_t base = (size_t)b * (RPB * NCH4) + 2 * t;   // += NCH4 per row

    f32x4 a0 = {0.f, 0.f, 0.f, 0.f};    // channels 8t..8t+3
    f32x4 a1 = {0.f, 0.f, 0.f, 0.f};    // channels 8t+4..8t+7

    #pragma unroll 8
    for (int r = 0; r < RPB; ++r) {
        a0 += x4[base];
        a1 += x4[base + 1];
        base += NCH4;
    }

    float* g = gsub + (size_t)(b & (NSUB - 1)) * NCH + 8 * t;
    atomicAdd(g + 0, a0.x); atomicAdd(g + 1, a0.y);
    atomicAdd(g + 2, a0.z); atomicAdd(g + 3, a0.w);
    atomicAdd(g + 4, a1.x); atomicAdd(g + 5, a1.y);
    atomicAdd(g + 6, a1.z); atomicAdd(g + 7, a1.w);
}

// g[c] = (cos(phi-f)*0.5+0.5)^10 + rw * sin(pi*p)^2 * cos(phi) * ws,
// phi = pacc*decay + mean.  Fast trig err ~1e-6 << 0.127 threshold.
__device__ __forceinline__ float gate1(float s, float fr, float pa, float spv,
                                       float dec, float wsc, float rw) {
    float phi = pa * dec + s * (1.0f / (float)BATCH);
    float t  = __cosf(phi - fr) * 0.5f + 0.5f;
    float t2 = t * t, t4 = t2 * t2, t8 = t4 * t4;
    float sp = __sinf((float)M_PI * spv);
    return t8 * t2 + rw * (sp * sp * __cosf(phi) * wsc);
}

// ---------------------------------------------------------------------------
// Pass 2: out = z * (1 - exp(-|z|)), z = x * g[c].
// Thread tid's f32x4 column is fixed across windows (c0 = 4*(tid&511)):
// reduce the NSUB sub-sums, compute its 4 g values in-registers (redundant
// across the grid but free), then stream 32 windows with a 4-deep prefetch
// pipeline. REGULAR loads for x; NT stores for out (both proven in R4).
// ---------------------------------------------------------------------------
__global__ __launch_bounds__(256) void gate_kernel(
        const float* __restrict__ x,
        const float* __restrict__ gsub,
        const float* __restrict__ freqs,
        const float* __restrict__ pdec,
        const float* __restrict__ wscl,
        const float* __restrict__ rwgt,
        const float* __restrict__ pacc,
        const float* __restrict__ spe,
        float* __restrict__ out) {
    const int tid = blockIdx.x * 256 + threadIdx.x;     // 0..524287
    const int c0 = (tid & 511) * 4;

    f32x4 s = {0.f, 0.f, 0.f, 0.f};
    #pragma unroll
    for (int k = 0; k < NSUB; ++k)
        s += *(const f32x4*)(gsub + (size_t)k * NCH + c0);

    const f32x4 fv = *(const f32x4*)(freqs + c0);
    const f32x4 qv = *(const f32x4*)(pacc + c0);
    const f32x4 ev = *(const f32x4*)(spe + c0);
    const float dec = pdec[0], wsc = wscl[0], rw = rwgt[0];

    f32x4 gv;
    gv.x = gate1(s.x, fv.x, qv.x, ev.x, dec, wsc, rw);
    gv.y = gate1(s.y, fv.y, qv.y, ev.y, dec, wsc, rw);
    gv.z = gate1(s.z, fv.z, qv.z, ev.z, dec, wsc, rw);
    gv.w = gate1(s.w, fv.w, qv.w, ev.w, dec, wsc, rw);

    const f32x4* __restrict__ x4 = (const f32x4*)x;
    f32x4* __restrict__ o4 = (f32x4*)out;

#define EMITP(v, jj)                                                      \
    do {                                                                  \
        f32x4 z = (v) * gv;                                               \
        f32x4 o;                                                          \
        o.x = z.x * (1.0f - __expf(-fabsf(z.x)));                         \
        o.y = z.y * (1.0f - __expf(-fabsf(z.y)));                         \
        o.z = z.z * (1.0f - __expf(-fabsf(z.z)));                         \
        o.w = z.w * (1.0f - __expf(-fabsf(z.w)));                         \
        __builtin_nontemporal_store(o, &o4[tid + (size_t)(jj) * STRIDE]); \
    } while (0)

    f32x4 v0 = x4[tid + 0 * (size_t)STRIDE];
    f32x4 v1 = x4[tid + 1 * (size_t)STRIDE];
    f32x4 v2 = x4[tid + 2 * (size_t)STRIDE];
    f32x4 v3 = x4[tid + 3 * (size_t)STRIDE];

    #pragma unroll
    for (int j = 0; j < 28; j += 4) {
        f32x4 n0 = x4[tid + (size_t)(j + 4) * STRIDE];
        f32x4 n1 = x4[tid + (size_t)(j + 5) * STRIDE];
        f32x4 n2 = x4[tid + (size_t)(j + 6) * STRIDE];
        f32x4 n3 = x4[tid + (size_t)(j + 7) * STRIDE];

        EMITP(v0, j + 0); EMITP(v1, j + 1); EMITP(v2, j + 2); EMITP(v3, j + 3);

        v0 = n0; v1 = n1; v2 = n2; v3 = n3;
    }
    EMITP(v0, 28); EMITP(v1, 29); EMITP(v2, 30); EMITP(v3, 31);
#undef EMITP
}

extern "C" void kernel_launch(void* const* d_in, const int* in_sizes, int n_in,
                              void* d_out, int out_size, void* d_ws, size_t ws_size,
                              hipStream_t stream) {
    const float* x     = (const float*)d_in[0];
    const float* freqs = (const float*)d_in[1];
    const float* pdec  = (const float*)d_in[2];
    const float* wscl  = (const float*)d_in[3];
    const float* rwgt  = (const float*)d_in[4];
    const float* pacc  = (const float*)d_in[5];
    const float* spe   = (const float*)d_in[6];
    float* out = (float*)d_out;

    float* gsub = (float*)d_ws;          // NSUB * 2048 floats = 64 KiB

    // zero the sub-accumulators every call (ws is poisoned once before
    // timing and never restored between replays)
    hipMemsetAsync(gsub, 0, NSUB * NCH * sizeof(float), stream);

    colsum_kernel<<<CS_BLOCKS, 256, 0, stream>>>(x, gsub);

    gate_kernel<<<GATE_BLOCKS, 256, 0, stream>>>(x, gsub, freqs, pdec, wscl,
                                                 rwgt, pacc, spe, out);
}